// Round 8
// baseline (305.788 us; speedup 1.0000x reference)
//
#include <hip/hip_runtime.h>
#include <hip/hip_bf16.h>

#define S_LEN 8192
#define HID 768
#define NH 12
#define HD 64
#define WIN 256

typedef __bf16 bf16x8 __attribute__((ext_vector_type(8)));
typedef float f32x4 __attribute__((ext_vector_type(4)));
using bf16_t = __hip_bfloat16;

#define MFMA(a, b, c) __builtin_amdgcn_mfma_f32_16x16x32_bf16(a, b, c, 0, 0, 0)

// async global->LDS, 16B/lane; LDS dest is wave-uniform base (+lane*16 in HW)
__device__ __forceinline__ void gl2lds16(const bf16_t* g, bf16_t* l) {
  __builtin_amdgcn_global_load_lds(
      (const __attribute__((address_space(1))) void*)g,
      (__attribute__((address_space(3))) void*)l, 16, 0, 0);
}

// ---- convert fp32 hidden states to bf16 ---------------------------------
__global__ __launch_bounds__(256) void conv_hs(const float* __restrict__ hs,
                                               bf16_t* __restrict__ hb) {
  int i = (blockIdx.x * 256 + threadIdx.x) * 4;
  float4 v = *reinterpret_cast<const float4*>(hs + i);
  union { ushort4 u; bf16_t b[4]; } H;
  H.b[0] = __float2bfloat16(v.x);
  H.b[1] = __float2bfloat16(v.y);
  H.b[2] = __float2bfloat16(v.z);
  H.b[3] = __float2bfloat16(v.w);
  *reinterpret_cast<ushort4*>(hb + i) = H.u;
}

// ---- weight transpose + bf16: Wt[z*768+n][k] = W_z[k][n] ----------------
__global__ __launch_bounds__(256) void transpose_w(const float* __restrict__ Wq,
                                                   const float* __restrict__ Wk,
                                                   const float* __restrict__ Wv,
                                                   bf16_t* __restrict__ Wt) {
  __shared__ float t[32][33];
  int z = blockIdx.z;
  const float* src = (z == 0) ? Wq : ((z == 1) ? Wk : Wv);
  int n0 = blockIdx.x * 32, k0 = blockIdx.y * 32;
  int tx = threadIdx.x, ty = threadIdx.y;  // 32 x 8
  for (int i = 0; i < 4; ++i)
    t[ty + i * 8][tx] = src[(k0 + ty + i * 8) * HID + n0 + tx];
  __syncthreads();
  bf16_t* dst = Wt + z * HID * HID;
  for (int i = 0; i < 4; ++i)
    dst[(n0 + ty + i * 8) * HID + k0 + tx] = __float2bfloat16(t[tx][ty + i * 8]);
}

// ---- fused QKV GEMM, 128x128 tile, BK=64, swizzled LDS (R5-proven) ------
__global__ __launch_bounds__(256) void qkv_gemm(
    const bf16_t* __restrict__ hb, const bf16_t* __restrict__ Wt,
    const float* __restrict__ bq, const float* __restrict__ bk,
    const float* __restrict__ bv,
    bf16_t* __restrict__ Qw, bf16_t* __restrict__ Kw, bf16_t* __restrict__ Vt) {
  __shared__ __align__(16) bf16_t sA[128 * 64];
  __shared__ __align__(16) bf16_t sB[128 * 64];
  int m0 = blockIdx.x * 128;
  int zq = blockIdx.y / 6;
  int nn0 = (blockIdx.y % 6) * 128;
  int n0g = zq * HID + nn0;
  int tid = threadIdx.x;
  int w = tid >> 6, lane = tid & 63, lm = lane & 15, qd = lane >> 4;
  int wm = w & 1, wn = w >> 1;

  // staging: LDS slot (row, c8) holds global chunk (row, c8 ^ (row&7))
  int srow = w * 8 + (lane >> 3);
  int sc8 = (lane & 7) ^ ((lane >> 3) & 7);
  const bf16_t* gA = hb + (m0 + srow) * HID + sc8 * 8;
  const bf16_t* gB = Wt + (n0g + srow) * HID + sc8 * 8;
  int sx0 = lm & 7;

  f32x4 acc[4][4] = {};
  for (int kk = 0; kk < HID; kk += 64) {
#pragma unroll
    for (int u = 0; u < 4; ++u) {
      gl2lds16(gA + (u * 32) * HID + kk, sA + u * 2048 + w * 512);
      gl2lds16(gB + (u * 32) * HID + kk, sB + u * 2048 + w * 512);
    }
    __syncthreads();
#pragma unroll
    for (int half = 0; half < 2; ++half) {
      int ca = (qd + 4 * half) ^ sx0;
      bf16x8 fa[4], fb[4];
#pragma unroll
      for (int i = 0; i < 4; ++i) {
        fa[i] = *reinterpret_cast<const bf16x8*>(
            sA + (wm * 64 + i * 16 + lm) * 64 + ca * 8);
        fb[i] = *reinterpret_cast<const bf16x8*>(
            sB + (wn * 64 + i * 16 + lm) * 64 + ca * 8);
      }
      if (zq == 2) {
#pragma unroll
        for (int i = 0; i < 4; ++i)
#pragma unroll
          for (int j = 0; j < 4; ++j)
            acc[i][j] = MFMA(fb[i], fa[j], acc[i][j]);  // C^T: rows=n
      } else {
#pragma unroll
        for (int i = 0; i < 4; ++i)
#pragma unroll
          for (int j = 0; j < 4; ++j)
            acc[i][j] = MFMA(fa[i], fb[j], acc[i][j]);  // rows=m
      }
    }
    __syncthreads();
  }

  if (zq != 2) {
    const float* bias = zq ? bk : bq;
    bf16_t* dst = zq ? Kw : Qw;
    float scale = zq ? 1.0f : 0.125f;  // fold 1/sqrt(D) into Q
#pragma unroll
    for (int j = 0; j < 4; ++j) {
      int nl = nn0 + wn * 64 + j * 16 + lm;
      float bb = bias[nl];
      int h = nl >> 6, d = nl & 63;
#pragma unroll
      for (int i = 0; i < 4; ++i)
#pragma unroll
        for (int r = 0; r < 4; ++r) {
          int m = m0 + wm * 64 + i * 16 + qd * 4 + r;
          dst[(h * S_LEN + m) * HD + d] =
              __float2bfloat16((acc[i][j][r] + bb) * scale);
        }
    }
  } else {
#pragma unroll
    for (int i = 0; i < 4; ++i)
#pragma unroll
      for (int r = 0; r < 4; ++r) {
        int nl = nn0 + wn * 64 + i * 16 + qd * 4 + r;  // nl == h*64+d
        float bb = bv[nl];
#pragma unroll
        for (int j = 0; j < 4; ++j) {
          int m = m0 + wm * 64 + j * 16 + lm;
          Vt[nl * S_LEN + m] = __float2bfloat16(acc[i][j][r] + bb);
        }
      }
  }
}

// ---- sliding-window attention: barrier-free, register-prefetched --------
// 1 block = (head, 64 queries); 4 waves x 16 queries; 64-key tiles.
// S^T orientation makes K/Q/V fragments contiguous b128 GLOBAL loads:
// K of tile t+1 is prefetched into a ping-pong register set; V of tile t
// issues at iter top (covered by S-MFMA+exp+P phase). No LDS staging, no
// __syncthreads; only the per-wave P round-trip uses LDS.
#define PST 76  // sP row stride (elems); measured 0 bank conflicts (R7)
__global__ __launch_bounds__(256, 2) void swa_kernel(
    const bf16_t* __restrict__ Qw, const bf16_t* __restrict__ Kw,
    const bf16_t* __restrict__ Vt, float* __restrict__ out) {
  __shared__ __align__(16) bf16_t sP[4 * 16 * PST];
  int h = blockIdx.y;
  int nb = blockIdx.x;
  int q0 = (((nb & 7) << 4) | (nb >> 3)) * 64;  // XCD-contiguous q-tiles
  int tid = threadIdx.x;
  int w = tid >> 6, lane = tid & 63, lm = lane & 15, qd = lane >> 4;
  int xb = q0 + w * 16;

  // Q B-frags (col=query=lm, k=d)
  int qoff = (h * S_LEN + xb + lm) * HD + qd * 8;
  bf16x8 aq0 = *reinterpret_cast<const bf16x8*>(Qw + qoff);
  bf16x8 aq1 = *reinterpret_cast<const bf16x8*>(Qw + qoff + 32);

  f32x4 o[4] = {};
  float lsum = 0.f;  // per-lane partial denom for query lm

  int y_begin = q0 - WIN; if (y_begin < 0) y_begin = 0;
  int y_end = q0 + 64 + WIN; if (y_end > S_LEN) y_end = S_LEN;
  int ntiles = (y_end - y_begin) >> 6;
  const bf16_t* Kh = Kw + h * S_LEN * HD;
  const bf16_t* Vh = Vt + h * HD * S_LEN;
  bf16_t* sPw = sP + w * 16 * PST;

  // K A-frags (row=key=nt*16+lm, k=d): ping-pong prefetch buffers
  bf16x8 kf[2][4][2];
#define LOADK(buf, y0)                                                   \
  {                                                                      \
    _Pragma("unroll") for (int nt = 0; nt < 4; ++nt) {                   \
      const bf16_t* kr = Kh + ((y0) + nt * 16 + lm) * HD + qd * 8;       \
      kf[buf][nt][0] = *reinterpret_cast<const bf16x8*>(kr);             \
      kf[buf][nt][1] = *reinterpret_cast<const bf16x8*>(kr + 32);        \
    }                                                                    \
  }

  LOADK(0, y_begin);

#pragma unroll 2
  for (int t = 0; t < ntiles; ++t) {
    int y0 = y_begin + t * 64;
    int cur = t & 1;
    if (t + 1 < ntiles) LOADK(cur ^ 1, y0 + 64);
    // V B-frags for this tile (col=d=nt*16+lm, k=key): issue now, used
    // after the S/exp/P phase (~500 cyc of latency cover)
    bf16x8 vf[4][2];
#pragma unroll
    for (int nt = 0; nt < 4; ++nt) {
      const bf16_t* vr = Vh + (nt * 16 + lm) * S_LEN + y0 + qd * 8;
      vf[nt][0] = *reinterpret_cast<const bf16x8*>(vr);
      vf[nt][1] = *reinterpret_cast<const bf16x8*>(vr + 32);
    }
    // --- S^T = K.Q^T: rows=key (qd*4+r), cols=query (lm)
    f32x4 s[4] = {};
#pragma unroll
    for (int nt = 0; nt < 4; ++nt) {
      s[nt] = MFMA(kf[cur][nt][0], aq0, s[nt]);
      s[nt] = MFMA(kf[cur][nt][1], aq1, s[nt]);
    }
    // --- p = exp(s); mask only edge tiles; pack 4 keys -> one b64 write
    int dy = y0 - q0;
    bool edge = (dy > 192) || (dy < -192);
#pragma unroll
    for (int nt = 0; nt < 4; ++nt) {
      union { ushort4 u; bf16_t b[4]; } P;
#pragma unroll
      for (int r = 0; r < 4; ++r) {
        float pv;
        if (edge) {
          int dlt = (y0 + nt * 16 + qd * 4 + r) - (xb + lm);  // key - query
          pv = (dlt <= WIN && dlt >= -WIN) ? __expf(s[nt][r]) : 0.f;
        } else {
          pv = __expf(s[nt][r]);
        }
        lsum += pv;
        P.b[r] = __float2bfloat16(pv);
      }
      *reinterpret_cast<ushort4*>(sPw + lm * PST + nt * 16 + qd * 4) = P.u;
    }
    // --- P A-frags (row=query=lm, k=key) from this wave's LDS region
    bf16x8 ap0 = *reinterpret_cast<const bf16x8*>(sPw + lm * PST + qd * 8);
    bf16x8 ap1 = *reinterpret_cast<const bf16x8*>(sPw + lm * PST + 32 + qd * 8);
    // --- O += P.V (rows=query, cols=d)
#pragma unroll
    for (int nt = 0; nt < 4; ++nt) {
      o[nt] = MFMA(ap0, vf[nt][0], o[nt]);
      o[nt] = MFMA(ap1, vf[nt][1], o[nt]);
    }
  }
  // --- reduce lsum across the 4 qd-groups (query lives at lane lm)
  lsum += __shfl_xor(lsum, 16);
  lsum += __shfl_xor(lsum, 32);
  // --- normalize + store fp32; inv for row qd*4+r held at lane qd*4+r
#pragma unroll
  for (int r = 0; r < 4; ++r) {
    float inv = 1.f / __shfl(lsum, qd * 4 + r);
    int x = xb + qd * 4 + r;
#pragma unroll
    for (int nt = 0; nt < 4; ++nt)
      out[x * HID + h * HD + nt * 16 + lm] = o[nt][r] * inv;
  }
}

extern "C" void kernel_launch(void* const* d_in, const int* in_sizes, int n_in,
                              void* d_out, int out_size, void* d_ws, size_t ws_size,
                              hipStream_t stream) {
  const float* hs = (const float*)d_in[0];
  const float* Wq = (const float*)d_in[1];
  const float* bq = (const float*)d_in[2];
  const float* Wk = (const float*)d_in[3];
  const float* bk = (const float*)d_in[4];
  const float* Wv = (const float*)d_in[5];
  const float* bv = (const float*)d_in[6];
  float* out = (float*)d_out;

  const int NSH = S_LEN * HID;
  const int NW = 3 * HID * HID;
  bf16_t* p = (bf16_t*)d_ws;
  bf16_t* hb = p; p += NSH;
  bf16_t* Wt = p; p += NW;
  bf16_t* Qw = p; p += NSH;
  bf16_t* Kw = p; p += NSH;
  bf16_t* Vt = p; p += NSH;

  conv_hs<<<dim3(NSH / 4 / 256), dim3(256), 0, stream>>>(hs, hb);
  transpose_w<<<dim3(24, 24, 3), dim3(32, 8), 0, stream>>>(Wq, Wk, Wv, Wt);
  qkv_gemm<<<dim3(64, 18), dim3(256), 0, stream>>>(
      hb, Wt, bq, bk, bv, Qw, Kw, Vt);
  swa_kernel<<<dim3(128, 12), dim3(256), 0, stream>>>(Qw, Kw, Vt, out);
}

// Round 9
// 234.356 us; speedup vs baseline: 1.3048x; 1.3048x over previous
//
#include <hip/hip_runtime.h>
#include <hip/hip_bf16.h>

#define S_LEN 8192
#define HID 768
#define NH 12
#define HD 64
#define WIN 256

typedef __bf16 bf16x8 __attribute__((ext_vector_type(8)));
typedef float f32x4 __attribute__((ext_vector_type(4)));
using bf16_t = __hip_bfloat16;

#define MFMA(a, b, c) __builtin_amdgcn_mfma_f32_16x16x32_bf16(a, b, c, 0, 0, 0)

// async global->LDS, 16B/lane; LDS dest is wave-uniform base (+lane*16 in HW)
__device__ __forceinline__ void gl2lds16(const bf16_t* g, bf16_t* l) {
  __builtin_amdgcn_global_load_lds(
      (const __attribute__((address_space(1))) void*)g,
      (__attribute__((address_space(3))) void*)l, 16, 0, 0);
}

// ---- convert fp32 hidden states to bf16 ---------------------------------
__global__ __launch_bounds__(256) void conv_hs(const float* __restrict__ hs,
                                               bf16_t* __restrict__ hb) {
  int i = (blockIdx.x * 256 + threadIdx.x) * 4;
  float4 v = *reinterpret_cast<const float4*>(hs + i);
  union { ushort4 u; bf16_t b[4]; } H;
  H.b[0] = __float2bfloat16(v.x);
  H.b[1] = __float2bfloat16(v.y);
  H.b[2] = __float2bfloat16(v.z);
  H.b[3] = __float2bfloat16(v.w);
  *reinterpret_cast<ushort4*>(hb + i) = H.u;
}

// ---- weight transpose + bf16: Wt[z*768+n][k] = W_z[k][n] ----------------
__global__ __launch_bounds__(256) void transpose_w(const float* __restrict__ Wq,
                                                   const float* __restrict__ Wk,
                                                   const float* __restrict__ Wv,
                                                   bf16_t* __restrict__ Wt) {
  __shared__ float t[32][33];
  int z = blockIdx.z;
  const float* src = (z == 0) ? Wq : ((z == 1) ? Wk : Wv);
  int n0 = blockIdx.x * 32, k0 = blockIdx.y * 32;
  int tx = threadIdx.x, ty = threadIdx.y;  // 32 x 8
  for (int i = 0; i < 4; ++i)
    t[ty + i * 8][tx] = src[(k0 + ty + i * 8) * HID + n0 + tx];
  __syncthreads();
  bf16_t* dst = Wt + z * HID * HID;
  for (int i = 0; i < 4; ++i)
    dst[(n0 + ty + i * 8) * HID + k0 + tx] = __float2bfloat16(t[tx][ty + i * 8]);
}

// ---- fused QKV GEMM, 128x128 tile, BK=64, swizzled LDS (R5-proven) ------
__global__ __launch_bounds__(256) void qkv_gemm(
    const bf16_t* __restrict__ hb, const bf16_t* __restrict__ Wt,
    const float* __restrict__ bq, const float* __restrict__ bk,
    const float* __restrict__ bv,
    bf16_t* __restrict__ Qw, bf16_t* __restrict__ Kw, bf16_t* __restrict__ Vt) {
  __shared__ __align__(16) bf16_t sA[128 * 64];
  __shared__ __align__(16) bf16_t sB[128 * 64];
  int m0 = blockIdx.x * 128;
  int zq = blockIdx.y / 6;
  int nn0 = (blockIdx.y % 6) * 128;
  int n0g = zq * HID + nn0;
  int tid = threadIdx.x;
  int w = tid >> 6, lane = tid & 63, lm = lane & 15, qd = lane >> 4;
  int wm = w & 1, wn = w >> 1;

  int srow = w * 8 + (lane >> 3);
  int sc8 = (lane & 7) ^ ((lane >> 3) & 7);
  const bf16_t* gA = hb + (m0 + srow) * HID + sc8 * 8;
  const bf16_t* gB = Wt + (n0g + srow) * HID + sc8 * 8;
  int sx0 = lm & 7;

  f32x4 acc[4][4] = {};
  for (int kk = 0; kk < HID; kk += 64) {
#pragma unroll
    for (int u = 0; u < 4; ++u) {
      gl2lds16(gA + (u * 32) * HID + kk, sA + u * 2048 + w * 512);
      gl2lds16(gB + (u * 32) * HID + kk, sB + u * 2048 + w * 512);
    }
    __syncthreads();
#pragma unroll
    for (int half = 0; half < 2; ++half) {
      int ca = (qd + 4 * half) ^ sx0;
      bf16x8 fa[4], fb[4];
#pragma unroll
      for (int i = 0; i < 4; ++i) {
        fa[i] = *reinterpret_cast<const bf16x8*>(
            sA + (wm * 64 + i * 16 + lm) * 64 + ca * 8);
        fb[i] = *reinterpret_cast<const bf16x8*>(
            sB + (wn * 64 + i * 16 + lm) * 64 + ca * 8);
      }
      if (zq == 2) {
#pragma unroll
        for (int i = 0; i < 4; ++i)
#pragma unroll
          for (int j = 0; j < 4; ++j)
            acc[i][j] = MFMA(fb[i], fa[j], acc[i][j]);  // C^T: rows=n
      } else {
#pragma unroll
        for (int i = 0; i < 4; ++i)
#pragma unroll
          for (int j = 0; j < 4; ++j)
            acc[i][j] = MFMA(fa[i], fb[j], acc[i][j]);  // rows=m
      }
    }
    __syncthreads();
  }

  if (zq != 2) {
    const float* bias = zq ? bk : bq;
    bf16_t* dst = zq ? Kw : Qw;
    float scale = zq ? 1.0f : 0.125f;  // fold 1/sqrt(D) into Q
#pragma unroll
    for (int j = 0; j < 4; ++j) {
      int nl = nn0 + wn * 64 + j * 16 + lm;
      float bb = bias[nl];
      int h = nl >> 6, d = nl & 63;
#pragma unroll
      for (int i = 0; i < 4; ++i)
#pragma unroll
        for (int r = 0; r < 4; ++r) {
          int m = m0 + wm * 64 + i * 16 + qd * 4 + r;
          dst[(h * S_LEN + m) * HD + d] =
              __float2bfloat16((acc[i][j][r] + bb) * scale);
        }
    }
  } else {
#pragma unroll
    for (int i = 0; i < 4; ++i)
#pragma unroll
      for (int r = 0; r < 4; ++r) {
        int nl = nn0 + wn * 64 + i * 16 + qd * 4 + r;  // nl == h*64+d
        float bb = bv[nl];
#pragma unroll
        for (int j = 0; j < 4; ++j) {
          int m = m0 + wm * 64 + j * 16 + lm;
          Vt[nl * S_LEN + m] = __float2bfloat16(acc[i][j][r] + bb);
        }
      }
  }
}

// ---- sliding-window attention: barrier-free, NAMED ping-pong regs -------
// 1 block = (head, 64 queries); 4 waves x 16 queries; 64-key tiles.
// S^T orientation => K/Q/V fragments are contiguous b128 GLOBAL loads.
// K(t+1) prefetched into the *other* named buffer (kA/kB, compile-time
// indices only — R8's kf[cur] runtime index spilled the array to scratch).
// No __syncthreads; only the per-wave P round-trip uses LDS.
#define PST 76  // sP row stride (elems); 0 bank conflicts measured (R7)
__global__ __launch_bounds__(256, 2) void swa_kernel(
    const bf16_t* __restrict__ Qw, const bf16_t* __restrict__ Kw,
    const bf16_t* __restrict__ Vt, float* __restrict__ out) {
  __shared__ __align__(16) bf16_t sP[4 * 16 * PST];
  int h = blockIdx.y;
  int nb = blockIdx.x;
  int q0 = (((nb & 7) << 4) | (nb >> 3)) * 64;  // XCD-contiguous q-tiles
  int tid = threadIdx.x;
  int w = tid >> 6, lane = tid & 63, lm = lane & 15, qd = lane >> 4;
  int xb = q0 + w * 16;

  // Q B-frags (col=query=lm, k=d)
  int qoff = (h * S_LEN + xb + lm) * HD + qd * 8;
  bf16x8 aq0 = *reinterpret_cast<const bf16x8*>(Qw + qoff);
  bf16x8 aq1 = *reinterpret_cast<const bf16x8*>(Qw + qoff + 32);

  f32x4 o[4] = {};
  float lsum = 0.f;  // per-lane partial denom for query lm

  int y_begin = q0 - WIN; if (y_begin < 0) y_begin = 0;
  int y_end = q0 + 64 + WIN; if (y_end > S_LEN) y_end = S_LEN;
  const bf16_t* Kh = Kw + h * S_LEN * HD;
  const bf16_t* Vh = Vt + h * HD * S_LEN;
  bf16_t* sPw = sP + w * 16 * PST;

  bf16x8 kA[4][2], kB[4][2];  // named ping-pong K A-frag buffers

#define LOADK(dst, yy)                                                   \
  {                                                                      \
    _Pragma("unroll") for (int nt = 0; nt < 4; ++nt) {                   \
      const bf16_t* kr = Kh + ((yy) + nt * 16 + lm) * HD + qd * 8;       \
      dst[nt][0] = *reinterpret_cast<const bf16x8*>(kr);                 \
      dst[nt][1] = *reinterpret_cast<const bf16x8*>(kr + 32);            \
    }                                                                    \
  }

#define PROC(kbuf, yy)                                                   \
  {                                                                      \
    bf16x8 vf[4][2];                                                     \
    _Pragma("unroll") for (int nt = 0; nt < 4; ++nt) {                   \
      const bf16_t* vr = Vh + (nt * 16 + lm) * S_LEN + (yy) + qd * 8;    \
      vf[nt][0] = *reinterpret_cast<const bf16x8*>(vr);                  \
      vf[nt][1] = *reinterpret_cast<const bf16x8*>(vr + 32);             \
    }                                                                    \
    f32x4 s[4] = {};                                                     \
    _Pragma("unroll") for (int nt = 0; nt < 4; ++nt) {                   \
      s[nt] = MFMA(kbuf[nt][0], aq0, s[nt]);                             \
      s[nt] = MFMA(kbuf[nt][1], aq1, s[nt]);                             \
    }                                                                    \
    int dy = (yy)-q0;                                                    \
    bool edge = (dy > 192) || (dy < -192);                               \
    _Pragma("unroll") for (int nt = 0; nt < 4; ++nt) {                   \
      union { ushort4 u; bf16_t b[4]; } P;                               \
      _Pragma("unroll") for (int r = 0; r < 4; ++r) {                    \
        float pv;                                                        \
        if (edge) {                                                      \
          int dlt = ((yy) + nt * 16 + qd * 4 + r) - (xb + lm);           \
          pv = (dlt <= WIN && dlt >= -WIN) ? __expf(s[nt][r]) : 0.f;     \
        } else {                                                         \
          pv = __expf(s[nt][r]);                                         \
        }                                                                \
        lsum += pv;                                                      \
        P.b[r] = __float2bfloat16(pv);                                   \
      }                                                                  \
      *reinterpret_cast<ushort4*>(sPw + lm * PST + nt * 16 + qd * 4) =   \
          P.u;                                                           \
    }                                                                    \
    bf16x8 ap0 =                                                         \
        *reinterpret_cast<const bf16x8*>(sPw + lm * PST + qd * 8);       \
    bf16x8 ap1 =                                                         \
        *reinterpret_cast<const bf16x8*>(sPw + lm * PST + 32 + qd * 8);  \
    _Pragma("unroll") for (int nt = 0; nt < 4; ++nt) {                   \
      o[nt] = MFMA(ap0, vf[nt][0], o[nt]);                               \
      o[nt] = MFMA(ap1, vf[nt][1], o[nt]);                               \
    }                                                                    \
  }

  int rem = (y_end - y_begin) >> 6;
  int y0 = y_begin;
  LOADK(kA, y0);
  while (true) {
    if (rem > 1) LOADK(kB, y0 + 64);
    PROC(kA, y0);
    y0 += 64;
    if (--rem == 0) break;
    if (rem > 1) LOADK(kA, y0 + 64);
    PROC(kB, y0);
    y0 += 64;
    if (--rem == 0) break;
  }

  // --- reduce lsum across the 4 qd-groups (query lives at lane lm)
  lsum += __shfl_xor(lsum, 16);
  lsum += __shfl_xor(lsum, 32);
  // --- normalize + store fp32; inv for row qd*4+r held at lane qd*4+r
#pragma unroll
  for (int r = 0; r < 4; ++r) {
    float inv = 1.f / __shfl(lsum, qd * 4 + r);
    int x = xb + qd * 4 + r;
#pragma unroll
    for (int nt = 0; nt < 4; ++nt)
      out[x * HID + h * HD + nt * 16 + lm] = o[nt][r] * inv;
  }
}

extern "C" void kernel_launch(void* const* d_in, const int* in_sizes, int n_in,
                              void* d_out, int out_size, void* d_ws, size_t ws_size,
                              hipStream_t stream) {
  const float* hs = (const float*)d_in[0];
  const float* Wq = (const float*)d_in[1];
  const float* bq = (const float*)d_in[2];
  const float* Wk = (const float*)d_in[3];
  const float* bk = (const float*)d_in[4];
  const float* Wv = (const float*)d_in[5];
  const float* bv = (const float*)d_in[6];
  float* out = (float*)d_out;

  const int NSH = S_LEN * HID;
  const int NW = 3 * HID * HID;
  bf16_t* p = (bf16_t*)d_ws;
  bf16_t* hb = p; p += NSH;
  bf16_t* Wt = p; p += NW;
  bf16_t* Qw = p; p += NSH;
  bf16_t* Kw = p; p += NSH;
  bf16_t* Vt = p; p += NSH;

  conv_hs<<<dim3(NSH / 4 / 256), dim3(256), 0, stream>>>(hs, hb);
  transpose_w<<<dim3(24, 24, 3), dim3(32, 8), 0, stream>>>(Wq, Wk, Wv, Wt);
  qkv_gemm<<<dim3(64, 18), dim3(256), 0, stream>>>(
      hb, Wt, bq, bk, bv, Qw, Kw, Vt);
  swa_kernel<<<dim3(128, 12), dim3(256), 0, stream>>>(Qw, Kw, Vt, out);
}

// Round 10
// 166.212 us; speedup vs baseline: 1.8398x; 1.4100x over previous
//
#include <hip/hip_runtime.h>
#include <hip/hip_bf16.h>

#define S_LEN 8192
#define HID 768
#define NH 12
#define HD 64
#define WIN 256

typedef __bf16 bf16x8 __attribute__((ext_vector_type(8)));
typedef float f32x4 __attribute__((ext_vector_type(4)));
using bf16_t = __hip_bfloat16;

#define MFMA(a, b, c) __builtin_amdgcn_mfma_f32_16x16x32_bf16(a, b, c, 0, 0, 0)

// async global->LDS, 16B/lane; LDS dest is wave-uniform base (+lane*16 in HW)
__device__ __forceinline__ void gl2lds16(const bf16_t* g, bf16_t* l) {
  __builtin_amdgcn_global_load_lds(
      (const __attribute__((address_space(1))) void*)g,
      (__attribute__((address_space(3))) void*)l, 16, 0, 0);
}

// ---- prep: fused hs fp32->bf16 convert + weight transpose ---------------
// blocks [0, 6144): convert; blocks [6144, 7872): transpose (24x24x3).
__global__ __launch_bounds__(256) void prep(const float* __restrict__ hs,
                                            bf16_t* __restrict__ hb,
                                            const float* __restrict__ Wq,
                                            const float* __restrict__ Wk,
                                            const float* __restrict__ Wv,
                                            bf16_t* __restrict__ Wt) {
  int bx = blockIdx.x;
  int tid = threadIdx.x;
  if (bx < 6144) {
    int i = (bx * 256 + tid) * 4;
    float4 v = *reinterpret_cast<const float4*>(hs + i);
    union { ushort4 u; bf16_t b[4]; } H;
    H.b[0] = __float2bfloat16(v.x);
    H.b[1] = __float2bfloat16(v.y);
    H.b[2] = __float2bfloat16(v.z);
    H.b[3] = __float2bfloat16(v.w);
    *reinterpret_cast<ushort4*>(hb + i) = H.u;
    return;
  }
  __shared__ float t[32][33];
  int b = bx - 6144;
  int z = b / 576;
  int r = b % 576;
  int n0 = (r / 24) * 32, k0 = (r % 24) * 32;
  const float* src = (z == 0) ? Wq : ((z == 1) ? Wk : Wv);
  int tx = tid & 31, ty = tid >> 5;  // 32 x 8
  for (int i = 0; i < 4; ++i)
    t[ty + i * 8][tx] = src[(k0 + ty + i * 8) * HID + n0 + tx];
  __syncthreads();
  bf16_t* dst = Wt + z * HID * HID;
  for (int i = 0; i < 4; ++i)
    dst[(n0 + ty + i * 8) * HID + k0 + tx] = __float2bfloat16(t[tx][ty + i * 8]);
}

// ---- fused QKV GEMM, 128x128 tile, BK=64, swizzled LDS (R5-proven) ------
__global__ __launch_bounds__(256) void qkv_gemm(
    const bf16_t* __restrict__ hb, const bf16_t* __restrict__ Wt,
    const float* __restrict__ bq, const float* __restrict__ bk,
    const float* __restrict__ bv,
    bf16_t* __restrict__ Qw, bf16_t* __restrict__ Kw, bf16_t* __restrict__ Vt) {
  __shared__ __align__(16) bf16_t sA[128 * 64];
  __shared__ __align__(16) bf16_t sB[128 * 64];
  int m0 = blockIdx.x * 128;
  int zq = blockIdx.y / 6;
  int nn0 = (blockIdx.y % 6) * 128;
  int n0g = zq * HID + nn0;
  int tid = threadIdx.x;
  int w = tid >> 6, lane = tid & 63, lm = lane & 15, qd = lane >> 4;
  int wm = w & 1, wn = w >> 1;

  int srow = w * 8 + (lane >> 3);
  int sc8 = (lane & 7) ^ ((lane >> 3) & 7);
  const bf16_t* gA = hb + (m0 + srow) * HID + sc8 * 8;
  const bf16_t* gB = Wt + (n0g + srow) * HID + sc8 * 8;
  int sx0 = lm & 7;

  f32x4 acc[4][4] = {};
  for (int kk = 0; kk < HID; kk += 64) {
#pragma unroll
    for (int u = 0; u < 4; ++u) {
      gl2lds16(gA + (u * 32) * HID + kk, sA + u * 2048 + w * 512);
      gl2lds16(gB + (u * 32) * HID + kk, sB + u * 2048 + w * 512);
    }
    __syncthreads();
#pragma unroll
    for (int half = 0; half < 2; ++half) {
      int ca = (qd + 4 * half) ^ sx0;
      bf16x8 fa[4], fb[4];
#pragma unroll
      for (int i = 0; i < 4; ++i) {
        fa[i] = *reinterpret_cast<const bf16x8*>(
            sA + (wm * 64 + i * 16 + lm) * 64 + ca * 8);
        fb[i] = *reinterpret_cast<const bf16x8*>(
            sB + (wn * 64 + i * 16 + lm) * 64 + ca * 8);
      }
      if (zq == 2) {
#pragma unroll
        for (int i = 0; i < 4; ++i)
#pragma unroll
          for (int j = 0; j < 4; ++j)
            acc[i][j] = MFMA(fb[i], fa[j], acc[i][j]);  // C^T: rows=n
      } else {
#pragma unroll
        for (int i = 0; i < 4; ++i)
#pragma unroll
          for (int j = 0; j < 4; ++j)
            acc[i][j] = MFMA(fa[i], fb[j], acc[i][j]);  // rows=m
      }
    }
    __syncthreads();
  }

  if (zq != 2) {
    const float* bias = zq ? bk : bq;
    bf16_t* dst = zq ? Kw : Qw;
    float scale = zq ? 1.0f : 0.125f;  // fold 1/sqrt(D) into Q
#pragma unroll
    for (int j = 0; j < 4; ++j) {
      int nl = nn0 + wn * 64 + j * 16 + lm;
      float bb = bias[nl];
      int h = nl >> 6, d = nl & 63;
#pragma unroll
      for (int i = 0; i < 4; ++i)
#pragma unroll
        for (int r = 0; r < 4; ++r) {
          int m = m0 + wm * 64 + i * 16 + qd * 4 + r;
          dst[(h * S_LEN + m) * HD + d] =
              __float2bfloat16((acc[i][j][r] + bb) * scale);
        }
    }
  } else {
#pragma unroll
    for (int i = 0; i < 4; ++i)
#pragma unroll
      for (int r = 0; r < 4; ++r) {
        int nl = nn0 + wn * 64 + i * 16 + qd * 4 + r;  // nl == h*64+d
        float bb = bv[nl];
#pragma unroll
        for (int j = 0; j < 4; ++j) {
          int m = m0 + wm * 64 + j * 16 + lm;
          Vt[nl * S_LEN + m] = __float2bfloat16(acc[i][j][r] + bb);
        }
      }
  }
}

// ---- sliding-window attention: LDS-staged K/V (R5), swizzled sP ---------
// 1 block = (head, 64 queries); 4 waves x 16 queries; 64-key tiles.
// sP uses the same XOR-16B swizzle as sK/sV instead of padding -> LDS is
// exactly 40KB -> 4 blocks/CU (was 41.2KB -> 3 blocks/CU).
__global__ __launch_bounds__(256, 4) void swa_kernel(
    const bf16_t* __restrict__ Qw, const bf16_t* __restrict__ Kw,
    const bf16_t* __restrict__ Vt, float* __restrict__ out) {
  __shared__ __align__(16) bf16_t sK[2][64 * 64];  // [key][d], swizzled chunks
  __shared__ __align__(16) bf16_t sV[2][64 * 64];  // [d][key], swizzled chunks
  __shared__ __align__(16) bf16_t sP[4 * 16 * 64]; // per-wave, swizzled chunks
  int h = blockIdx.y;
  int nb = blockIdx.x;
  int q0 = (((nb & 7) << 4) | (nb >> 3)) * 64;  // XCD-contiguous q-tiles
  int tid = threadIdx.x;
  int w = tid >> 6, lane = tid & 63, lm = lane & 15, qd = lane >> 4;
  int xb = q0 + w * 16;

  // Q B-frags (col=query=lm, k=d)
  int qoff = (h * S_LEN + xb + lm) * HD + qd * 8;
  bf16x8 aq0 = *reinterpret_cast<const bf16x8*>(Qw + qoff);
  bf16x8 aq1 = *reinterpret_cast<const bf16x8*>(Qw + qoff + 32);

  f32x4 o[4] = {};
  float lsum = 0.f;  // per-lane partial denom for query lm

  int y_begin = q0 - WIN; if (y_begin < 0) y_begin = 0;
  int y_end = q0 + 64 + WIN; if (y_end > S_LEN) y_end = S_LEN;
  int ntiles = (y_end - y_begin) >> 6;
  const bf16_t* Kh = Kw + h * S_LEN * HD;
  const bf16_t* Vh = Vt + h * HD * S_LEN;
  bf16_t* sPw = sP + w * 16 * 64;

  int srow = w * 8 + (lane >> 3);
  int sc8 = (lane & 7) ^ ((lane >> 3) & 7);
  int sx0 = lm & 7;

#define STAGE(y0, b)                                                    \
  {                                                                     \
    const bf16_t* kg = Kh + ((y0) + srow) * HD + sc8 * 8;               \
    gl2lds16(kg, &sK[b][w * 512]);                                      \
    gl2lds16(kg + 32 * HD, &sK[b][2048 + w * 512]);                     \
    const bf16_t* vg = Vh + srow * S_LEN + (y0) + sc8 * 8;              \
    gl2lds16(vg, &sV[b][w * 512]);                                      \
    gl2lds16(vg + 32 * S_LEN, &sV[b][2048 + w * 512]);                  \
  }

  STAGE(y_begin, 0);
  __syncthreads();

  for (int t = 0; t < ntiles; ++t) {
    int y0 = y_begin + t * 64;
    if (t + 1 < ntiles) STAGE(y0 + 64, (t + 1) & 1);
    int b = t & 1;
    // --- S^T = K.Q^T: rows=key (qd*4+r), cols=query (lm)
    f32x4 s[4] = {};
#pragma unroll
    for (int nt = 0; nt < 4; ++nt) {
      const bf16_t* kr = &sK[b][(nt * 16 + lm) * 64];
      bf16x8 b0 = *reinterpret_cast<const bf16x8*>(kr + (qd ^ sx0) * 8);
      bf16x8 b1 = *reinterpret_cast<const bf16x8*>(kr + ((qd + 4) ^ sx0) * 8);
      s[nt] = MFMA(b0, aq0, s[nt]);
      s[nt] = MFMA(b1, aq1, s[nt]);
    }
    // --- p = exp(s); mask only edge tiles; pack 4 keys -> one b64 write
    // sP slot: row=query lm, 16B chunk (2nt+(qd>>1)) ^ (lm&7), half qd&1
    int dy = y0 - q0;
    bool edge = (dy > 192) || (dy < -192);
#pragma unroll
    for (int nt = 0; nt < 4; ++nt) {
      union { ushort4 u; bf16_t b[4]; } P;
#pragma unroll
      for (int r = 0; r < 4; ++r) {
        float pv;
        if (edge) {
          int dlt = (y0 + nt * 16 + qd * 4 + r) - (xb + lm);  // key - query
          pv = (dlt <= WIN && dlt >= -WIN) ? __expf(s[nt][r]) : 0.f;
        } else {
          pv = __expf(s[nt][r]);
        }
        lsum += pv;
        P.b[r] = __float2bfloat16(pv);
      }
      *reinterpret_cast<ushort4*>(
          sPw + lm * 64 + (((2 * nt + (qd >> 1)) ^ sx0) * 8) + (qd & 1) * 4) =
          P.u;
    }
    // --- P A-frags (row=query=lm, k=key): chunk qd / qd+4, same swizzle
    bf16x8 ap0 =
        *reinterpret_cast<const bf16x8*>(sPw + lm * 64 + ((qd ^ sx0) * 8));
    bf16x8 ap1 = *reinterpret_cast<const bf16x8*>(sPw + lm * 64 +
                                                  (((qd + 4) ^ sx0) * 8));
    // --- O += P.V (rows=query, cols=d)
#pragma unroll
    for (int nt = 0; nt < 4; ++nt) {
      const bf16_t* vr = &sV[b][(nt * 16 + lm) * 64];
      bf16x8 v0 = *reinterpret_cast<const bf16x8*>(vr + (qd ^ sx0) * 8);
      bf16x8 v1 = *reinterpret_cast<const bf16x8*>(vr + ((qd + 4) ^ sx0) * 8);
      o[nt] = MFMA(ap0, v0, o[nt]);
      o[nt] = MFMA(ap1, v1, o[nt]);
    }
    __syncthreads();  // drains prefetch + protects K/V buffers
  }
  // --- reduce lsum across the 4 qd-groups (query lives at lane lm)
  lsum += __shfl_xor(lsum, 16);
  lsum += __shfl_xor(lsum, 32);
  // --- normalize + store fp32; inv for row qd*4+r held at lane qd*4+r
#pragma unroll
  for (int r = 0; r < 4; ++r) {
    float inv = 1.f / __shfl(lsum, qd * 4 + r);
    int x = xb + qd * 4 + r;
#pragma unroll
    for (int nt = 0; nt < 4; ++nt)
      out[x * HID + h * HD + nt * 16 + lm] = o[nt][r] * inv;
  }
}

extern "C" void kernel_launch(void* const* d_in, const int* in_sizes, int n_in,
                              void* d_out, int out_size, void* d_ws, size_t ws_size,
                              hipStream_t stream) {
  const float* hs = (const float*)d_in[0];
  const float* Wq = (const float*)d_in[1];
  const float* bq = (const float*)d_in[2];
  const float* Wk = (const float*)d_in[3];
  const float* bk = (const float*)d_in[4];
  const float* Wv = (const float*)d_in[5];
  const float* bv = (const float*)d_in[6];
  float* out = (float*)d_out;

  const int NSH = S_LEN * HID;
  const int NW = 3 * HID * HID;
  bf16_t* p = (bf16_t*)d_ws;
  bf16_t* hb = p; p += NSH;
  bf16_t* Wt = p; p += NW;
  bf16_t* Qw = p; p += NSH;
  bf16_t* Kw = p; p += NSH;
  bf16_t* Vt = p; p += NSH;

  prep<<<dim3(6144 + 1728), dim3(256), 0, stream>>>(hs, hb, Wq, Wk, Wv, Wt);
  qkv_gemm<<<dim3(64, 18), dim3(256), 0, stream>>>(
      hb, Wt, bq, bk, bv, Qw, Kw, Vt);
  swa_kernel<<<dim3(128, 12), dim3(256), 0, stream>>>(Qw, Kw, Vt, out);
}